// Round 17
// baseline (636.985 us; speedup 1.0000x reference)
//
#include <hip/hip_runtime.h>

#define NEG 0.01f
__device__ __forceinline__ float lrelu(float v){ return v >= 0.f ? v : NEG * v; }

typedef short bf16x8 __attribute__((ext_vector_type(8)));   // 8 bf16 = 4 VGPRs
typedef float f32x4 __attribute__((ext_vector_type(4)));
typedef unsigned short u16;

__device__ __forceinline__ u16 f2bf(float f) {   // RNE f32 -> bf16 (finite inputs)
  unsigned u = __float_as_uint(f);
  return (u16)((u + 0x7FFFu + ((u >> 16) & 1u)) >> 16);
}
__device__ __forceinline__ float bflo(unsigned u){ return __uint_as_float(u << 16); }
__device__ __forceinline__ float bfhi(unsigned u){ return __uint_as_float(u & 0xffff0000u); }
__device__ __forceinline__ float bfu(u16 v){ return __uint_as_float((unsigned)v << 16); }

__device__ __forceinline__ float fma4(float4 wv, float4 hv, float acc) {
  return fmaf(wv.x, hv.x, fmaf(wv.y, hv.y, fmaf(wv.z, hv.z, fmaf(wv.w, hv.w, acc))));
}

// ============================ RULES (carried) ============================
// (R2)  no runtime-bound loop may index a register array — full unroll only.
// (R9)  dense head in wave 0 only (s_waitcnt+wave_barrier ordering).
// (R14) MFMA 16x16x32 bf16 map (verified): A row m=l&15, k=8*(l>>4)+i; B col
//       n=l&15; C/D row=(l>>4)*4+reg, col=l&15.
// (R15) H2 bf16 from birth; residual rounds ONCE.
// (R16) VGPR cliff at 64. Nothing live across barriers + hard cap.
// (R20/R31) serial p-loops & paired-patch blocks: dead ends.
// (R22) unroll-1 on hot weight loops serializes latency.
// (R25) H2B row stride 36 u32 (144B). (R26) split retired. (R27) full stash.
// (R29) stage-4 BARRIER-FREE: in-place H2B RMW on wave-own rows (holds under
//       R35 swap: wave w's px rows {16w..} for reads AND writes).
// (R30) SBH/G bf16 [81][40]: arena 6156 dw.
// (R32) LIMITER = per-CU issue floor; r15 showed VALU-issue no longer binds —
//       residual mass is LDS-pipe (scalar u16 epilogues).
// (R33) stage-6 = MFMA conv3, C2S bf16 [56][40].
// (R34) stage-1 = MFMA conv1, A/B from XS in regs, wb1 K-padded.
// (R35) stages 1/2a/4 use SWAPPED operands: mfma(weights, acts) -> D[oc][px];
//       lane holds 4 CONSECUTIVE oc at one px -> epilogues are uint2 LDS ops
//       (stage-1 32 b16 stores->6 b64; 2a 24->9; st-4 RMW 48->12). Biases via
//       aligned float4. Bit-identical math (same dot products, same assoc,
//       same rounding points) -> absmax must stay 3.051758e-05 EXACTLY.
// (R36) r16 bench = infra failure ("container failed twice", no profile);
//       code re-audited (fragment map, bounds, R29 ownership, clamps) — no
//       bug found. Resubmitted unchanged.

// -------- LDS arena: S[6156] dw = 24624 B -> 6 blocks/CU --------
// Phase A (0-4): H2B@0 u32[81][36] (2916) | SBH@2916 u16[81][40] (1620) |
//   XS@4536(121; dies at st-1 end) | G@4536 u16[81][40] (1620, born 2a).
// Stage 4: in-place H2B->H4 u16[81][72] @0 (R29, no barrier).
// Stage 5: A-reads H4@0 stride 144B, writes C2S@2916 u16[56][40].
// Stage 6: reads C2S@2916, writes C3S@1600 (over dead H4).
// Phase C: C3S@1600(200) D1P@1800(256) D1@2056 D2@2120 D3@2152 D4@2168.
#define H2B  0
#define SBH  2916
#define XS   4536
#define G0   4536
#define H4   0
#define C2S  2916
#define C3S  1600
#define D1P  1800
#define D1   2056
#define D2   2120
#define D3   2152
#define D4   2168

// repack (all bf16 u16): wb2 [tap9][oc32][ic64] @0 (18432)
//   wtpg [96 n][64 k] @18432 (6144) | wob [64 n][32 k] @24576 (2048)
//   wb3b [tap9][16 n][32 k] @26624 (4608; n>=8 zero)
//   wb1  [64 n][32 k] @31232 (2048; k>=9 zero)        total 33280 u16
__global__ void repack_w23(const float* __restrict__ w2, const float* __restrict__ w3,
                           const float* __restrict__ wt, const float* __restrict__ wp,
                           const float* __restrict__ wg, const float* __restrict__ wo,
                           const float* __restrict__ w1, float* __restrict__ pw) {
  int idx = blockIdx.x * 256 + threadIdx.x;
  u16* u = (u16*)pw;
  for (int i = idx; i < 33280; i += gridDim.x * 256) {
    if (i < 18432) {
      int ic = i & 63, oc = (i >> 6) & 31, tap = i >> 11;
      u[i] = f2bf(w2[(oc * 64 + ic) * 9 + tap]);
    } else if (i < 24576) {
      int j = i - 18432;                 // wtpg
      int k = j & 63, n = j >> 6;
      float v = (n < 32) ? wt[n * 64 + k]
              : (n < 64) ? wp[(n - 32) * 64 + k]
                         : wg[(n - 64) * 64 + k];
      u[i] = f2bf(v);
    } else if (i < 26624) {
      int j = i - 24576;                 // wob: [oc][ic]
      u[i] = f2bf(wo[j]);
    } else if (i < 31232) {
      int j = i - 26624;                 // wb3b: [tap][16 n][32 ic]
      int ic = j & 31, n = (j >> 5) & 15, tap = j >> 9;
      u[i] = (n < 8) ? f2bf(w3[(n * 32 + ic) * 9 + tap]) : (u16)0;
    } else {
      int j = i - 31232;                 // wb1: [64 n][32 k], k=tap
      int k = j & 31, n = j >> 5;
      u[i] = (k < 9) ? f2bf(w1[n * 9 + k]) : (u16)0;
    }
  }
}

// stage-4 B-fragment: bf16(attn*G) for px row ar, k-slot kg (R35)
__device__ __forceinline__ bf16x8 st4_afrag(const float* S, int ar, int kg) {
  const uint4 sv = *(const uint4*)((const u16*)&S[SBH] + ar * 40 + kg * 8);
  const uint4 gv = *(const uint4*)((const u16*)&S[G0] + ar * 40 + kg * 8);
  unsigned q0 = (unsigned)f2bf(bflo(sv.x) * bflo(gv.x)) |
                ((unsigned)f2bf(bfhi(sv.x) * bfhi(gv.x)) << 16);
  unsigned q1 = (unsigned)f2bf(bflo(sv.y) * bflo(gv.y)) |
                ((unsigned)f2bf(bfhi(sv.y) * bfhi(gv.y)) << 16);
  unsigned q2 = (unsigned)f2bf(bflo(sv.z) * bflo(gv.z)) |
                ((unsigned)f2bf(bfhi(sv.z) * bfhi(gv.z)) << 16);
  unsigned q3 = (unsigned)f2bf(bflo(sv.w) * bflo(gv.w)) |
                ((unsigned)f2bf(bfhi(sv.w) * bfhi(gv.w)) << 16);
  union { uint4 u; bf16x8 b; } v; v.u = (uint4){q0, q1, q2, q3}; return v.b;
}

__global__ __launch_bounds__(256, 8) __attribute__((amdgpu_num_vgpr(64)))
void braggnn_fused(
    const float* __restrict__ x,
    const u16* __restrict__ wb1, const float* __restrict__ b1,
    const u16* __restrict__ wtpg,
    const float* __restrict__ bt, const float* __restrict__ bp,
    const float* __restrict__ bg,
    const u16* __restrict__ wob, const float* __restrict__ bo,
    const u16* __restrict__ wb2, const u16* __restrict__ wb3b,
    const float* __restrict__ b2, const float* __restrict__ b3,
    const float* __restrict__ dw1, const float* __restrict__ db1,
    const float* __restrict__ dw2, const float* __restrict__ db2,
    const float* __restrict__ dw3, const float* __restrict__ db3,
    const float* __restrict__ dw4, const float* __restrict__ db4,
    const float* __restrict__ dw5, const float* __restrict__ db5,
    float* __restrict__ out)
{
  const int b = blockIdx.x;
  const int t = threadIdx.x;

  __shared__ __align__(16) float S[6156];   // 24624 B

  // ---- stage 0: load 11x11 patch ----
  if (t < 121) S[XS + t] = x[(size_t)b * 121 + t];
  __syncthreads();

  // ---- stage 1 (R34/R35): conv1 as mfma(W, acts) -> D[oc][px] ----
  {
    const int lane = t & 63, wid = t >> 6;
    const int c = lane & 15, kg = lane >> 4;
    const u16* wpp = wb1 + c * 32 + kg * 8;
    const bf16x8 A0 = *(const bf16x8*)(wpp);          // oc-tile 0
    const bf16x8 A1 = *(const bf16x8*)(wpp + 512);
    const bf16x8 A2 = *(const bf16x8*)(wpp + 1024);
    const bf16x8 A3 = *(const bf16x8*)(wpp + 1536);
    const float4 bb0 = *(const float4*)&b1[kg * 4];
    const float4 bb1 = *(const float4*)&b1[16 + kg * 4];
    const float4 bb2 = *(const float4*)&b1[32 + kg * 4];
    const float4 bb3 = *(const float4*)&b1[48 + kg * 4];
    const f32x4 z = {0.f, 0.f, 0.f, 0.f};
    u16* Hw = (u16*)S;      // H2B u16 view: idx = px*72 + oc
#pragma unroll 1
    for (int r2 = 0; r2 < 2; r2++) {
      const int nt = wid + 4 * r2;
      if (nt >= 6) break;                   // wave-uniform
      int pxr = nt * 16 + c; if (pxr > 80) pxr = 80;   // clamp garbage cols
      const int ay = pxr / 9, ax = pxr - ay * 9;
      const float* xr = &S[XS + ay * 11 + ax];
      union { uint4 u; bf16x8 bv; } av;
      if (kg == 0) {        // taps 0..7 (tap=ky*3+kx)
        av.u.x = (unsigned)f2bf(xr[0])  | ((unsigned)f2bf(xr[1])  << 16);
        av.u.y = (unsigned)f2bf(xr[2])  | ((unsigned)f2bf(xr[11]) << 16);
        av.u.z = (unsigned)f2bf(xr[12]) | ((unsigned)f2bf(xr[13]) << 16);
        av.u.w = (unsigned)f2bf(xr[22]) | ((unsigned)f2bf(xr[23]) << 16);
      } else if (kg == 1) { // tap 8; k>=10 hit zero B rows
        av.u = (uint4){(unsigned)f2bf(xr[24]), 0u, 0u, 0u};
      } else {              // k>=16: zero
        av.u = (uint4){0u, 0u, 0u, 0u};
      }
      const f32x4 C0 = __builtin_amdgcn_mfma_f32_16x16x32_bf16(A0, av.bv, z, 0, 0, 0);
      const f32x4 C1 = __builtin_amdgcn_mfma_f32_16x16x32_bf16(A1, av.bv, z, 0, 0, 0);
      const f32x4 C2 = __builtin_amdgcn_mfma_f32_16x16x32_bf16(A2, av.bv, z, 0, 0, 0);
      const f32x4 C3 = __builtin_amdgcn_mfma_f32_16x16x32_bf16(A3, av.bv, z, 0, 0, 0);
      const int px = nt * 16 + c;
      if (px <= 80) {       // 4 consecutive oc at this px -> one uint2 each
#define EPI1(ACC, MT, BB) { \
        uint2 pk; \
        pk.x = (unsigned)f2bf(ACC[0] + BB.x) | ((unsigned)f2bf(ACC[1] + BB.y) << 16); \
        pk.y = (unsigned)f2bf(ACC[2] + BB.z) | ((unsigned)f2bf(ACC[3] + BB.w) << 16); \
        *(uint2*)&Hw[px * 72 + (MT) * 16 + kg * 4] = pk; }
        EPI1(C0, 0, bb0) EPI1(C1, 1, bb1) EPI1(C2, 2, bb2) EPI1(C3, 3, bb3)
      }
    }
  }
  __syncthreads();

  // ---- stage 2a (R35): theta/phi/g via mfma(W, acts); uint2 epilogues ----
  {
    const int lane = t & 63, wid = t >> 6;
    const int c = lane & 15, kg = lane >> 4;
    const char* Sb = (const char*)S;          // H2B at byte 0, 144 B/row
    u16* SBu = (u16*)&S[SBH];
    u16* Gp  = (u16*)&S[G0];
    const f32x4 z = {0.f, 0.f, 0.f, 0.f};
#pragma unroll 1
    for (int r2 = 0; r2 < 2; r2++) {
      const int nt = wid + 4 * r2;
      if (nt >= 6) break;                   // wave-uniform
      int pxr = nt * 16 + c; if (pxr > 80) pxr = 80;
      const bf16x8 bA = *(const bf16x8*)(Sb + pxr * 144 + kg * 16);        // ks=0
      const bf16x8 bB = *(const bf16x8*)(Sb + pxr * 144 + 64 + kg * 16);   // ks=1
      f32x4 T0 = z, T1 = z, P0 = z, P1 = z, Gv0 = z, Gv1 = z;
#define MT2A(ACC, MT) { \
      const u16* al = wtpg + ((MT) * 16 + c) * 64 + kg * 8; \
      const bf16x8 a0_ = *(const bf16x8*)(al); \
      const bf16x8 a1_ = *(const bf16x8*)(al + 32); \
      ACC = __builtin_amdgcn_mfma_f32_16x16x32_bf16(a0_, bA, ACC, 0, 0, 0); \
      ACC = __builtin_amdgcn_mfma_f32_16x16x32_bf16(a1_, bB, ACC, 0, 0, 0); }
      MT2A(T0, 0) MT2A(T1, 1) MT2A(P0, 2) MT2A(P1, 3) MT2A(Gv0, 4) MT2A(Gv1, 5)
      const int px = nt * 16 + c;
      if (px <= 80) {
#define EPI2A(TT, PP, GG, G) { \
        const float4 btv = *(const float4*)&bt[(G) * 16 + kg * 4]; \
        const float4 bpv = *(const float4*)&bp[(G) * 16 + kg * 4]; \
        const float4 bgv = *(const float4*)&bg[(G) * 16 + kg * 4]; \
        uint2 pk; \
        pk.x = (unsigned)f2bf((TT[0] + btv.x) * (PP[0] + bpv.x)) | \
               ((unsigned)f2bf((TT[1] + btv.y) * (PP[1] + bpv.y)) << 16); \
        pk.y = (unsigned)f2bf((TT[2] + btv.z) * (PP[2] + bpv.z)) | \
               ((unsigned)f2bf((TT[3] + btv.w) * (PP[3] + bpv.w)) << 16); \
        *(uint2*)&SBu[px * 40 + (G) * 16 + kg * 4] = pk; \
        uint2 gk; \
        gk.x = (unsigned)f2bf(GG[0] + bgv.x) | ((unsigned)f2bf(GG[1] + bgv.y) << 16); \
        gk.y = (unsigned)f2bf(GG[2] + bgv.z) | ((unsigned)f2bf(GG[3] + bgv.w) << 16); \
        *(uint2*)&Gp[px * 40 + (G) * 16 + kg * 4] = gk; }
        EPI2A(T0, P0, Gv0, 0)
        EPI2A(T1, P1, Gv1, 1)
      }
    }
  }
  __syncthreads();

  // ---- stage 2 pass B: softmax over W (9), bf16 in/out, f32 compute (R30) ----
  {
    u16* SBu = (u16*)&S[SBH];
    auto sm = [&](int r) {
      const int oc = r & 31, y = r >> 5;
      const int base = y * 9 * 40 + oc;       // u16 index; px = y*9+k
      float v[9]; float m = -1e30f;
#pragma unroll
      for (int k = 0; k < 9; k++) { v[k] = bfu(SBu[base + k * 40]); m = fmaxf(m, v[k]); }
      float s = 0.f;
#pragma unroll
      for (int k = 0; k < 9; k++) { v[k] = __expf(v[k] - m); s += v[k]; }
      const float inv = 1.f / s;
#pragma unroll
      for (int k = 0; k < 9; k++) SBu[base + k * 40] = f2bf(v[k] * inv);
    };
    sm(t);
    if (t < 32) sm(256 + t);
  }
  __syncthreads();

  // ---- stage 4 (R29/R35): wo 1x1 as mfma(W, acts), BARRIER-FREE uint2 RMW ----
  {
    const int lane = t & 63, wid = t >> 6;
    const int c = lane & 15, kg = lane >> 4;
    const u16* wpp = wob + c * 32 + kg * 8;
    const bf16x8 A0 = *(const bf16x8*)(wpp);
    const bf16x8 A1 = *(const bf16x8*)(wpp + 512);
    const bf16x8 A2 = *(const bf16x8*)(wpp + 1024);
    const bf16x8 A3 = *(const bf16x8*)(wpp + 1536);
    const float4 bo0 = *(const float4*)&bo[kg * 4];
    const float4 bo1 = *(const float4*)&bo[16 + kg * 4];
    const float4 bo2 = *(const float4*)&bo[32 + kg * 4];
    const float4 bo3 = *(const float4*)&bo[48 + kg * 4];
    const f32x4 z = {0.f, 0.f, 0.f, 0.f};
    u16* Hw = (u16*)S;      // H2B/H4 u16 view: idx = px*72 + oc (same address!)
#pragma unroll 1
    for (int r2 = 0; r2 < 2; r2++) {
      const int nt = wid + 4 * r2;
      if (nt >= 6) break;                   // wave-uniform
      int pxr = nt * 16 + c; if (pxr > 80) pxr = 80;
      const bf16x8 bv = st4_afrag(S, pxr, kg);
      const f32x4 C0 = __builtin_amdgcn_mfma_f32_16x16x32_bf16(A0, bv, z, 0, 0, 0);
      const f32x4 C1 = __builtin_amdgcn_mfma_f32_16x16x32_bf16(A1, bv, z, 0, 0, 0);
      const f32x4 C2 = __builtin_amdgcn_mfma_f32_16x16x32_bf16(A2, bv, z, 0, 0, 0);
      const f32x4 C3 = __builtin_amdgcn_mfma_f32_16x16x32_bf16(A3, bv, z, 0, 0, 0);
      const int px = nt * 16 + c;
      if (px <= 80) {       // RMW: one uint2 read + one uint2 write per oc-tile
#define EPI4(ACC, MT, BB) { \
        uint2 h = *(uint2*)&Hw[px * 72 + (MT) * 16 + kg * 4]; \
        const float v0 = lrelu((ACC[0] + bflo(h.x)) + BB.x); \
        const float v1 = lrelu((ACC[1] + bfhi(h.x)) + BB.y); \
        const float v2 = lrelu((ACC[2] + bflo(h.y)) + BB.z); \
        const float v3 = lrelu((ACC[3] + bfhi(h.y)) + BB.w); \
        uint2 pk; \
        pk.x = (unsigned)f2bf(v0) | ((unsigned)f2bf(v1) << 16); \
        pk.y = (unsigned)f2bf(v2) | ((unsigned)f2bf(v3) << 16); \
        *(uint2*)&Hw[px * 72 + (MT) * 16 + kg * 4] = pk; }
        EPI4(C0, 0, bo0) EPI4(C1, 1, bo1) EPI4(C2, 2, bo2) EPI4(C3, 3, bo3)
      }
    }
  }
  __syncthreads();

  // ---- stage 5 (R14): conv2 64->32 3x3 as bf16 MFMA 16x16x32 ----
  {
    const int lane = t & 63, wid = t >> 6;
    const int m = lane & 15, kg = lane >> 4;      // A row, k-group
    const int opx = wid * 16 + m;                 // output px this lane feeds
    const int oy = opx / 7, ox = opx - oy * 7;
    const char* Sb = (const char*)S;
    int aoff = (oy * 9 + ox) * 144 + kg * 16;     // bytes into H4@0 (144 B/row)
    const u16* wbl = wb2 + (lane & 15) * 64 + kg * 8;
    f32x4 acc0 = {0.f, 0.f, 0.f, 0.f}, acc1 = {0.f, 0.f, 0.f, 0.f};
#pragma unroll 1
    for (int ky = 0; ky < 3; ky++) {
#pragma unroll
      for (int kx = 0; kx < 3; kx++) {
#pragma unroll
        for (int ks = 0; ks < 2; ks++) {
          const bf16x8 av = *(const bf16x8*)(Sb + (aoff + kx * 144 + ks * 64));
          const bf16x8 b0v = *(const bf16x8*)(wbl + kx * 2048 + ks * 32);
          const bf16x8 b1v = *(const bf16x8*)(wbl + kx * 2048 + ks * 32 + 1024);
          acc0 = __builtin_amdgcn_mfma_f32_16x16x32_bf16(av, b0v, acc0, 0, 0, 0);
          acc1 = __builtin_amdgcn_mfma_f32_16x16x32_bf16(av, b1v, acc1, 0, 0, 0);
        }
      }
      aoff += 9 * 144;        // next ky input row
      wbl  += 3 * 2048;       // next ky tap group
    }
    // epilogue (R33): bias + lrelu -> C2S bf16 [56 rows][40 u16] @2916
    u16* C2u = (u16*)&S[C2S];
#pragma unroll
    for (int nt = 0; nt < 2; nt++) {
      const f32x4 accv = nt ? acc1 : acc0;
      const int oc = nt * 16 + (lane & 15);
      const float bv = b2[oc];
#pragma unroll
      for (int r = 0; r < 4; r++) {
        const int px = wid * 16 + kg * 4 + r;     // C row = (lane>>4)*4 + reg
        if (px < 49) {
          const int y = px / 7, xx = px - y * 7;
          C2u[(y * 8 + xx) * 40 + oc] = f2bf(lrelu(accv[r] + bv));
        }
      }
    }
  }
  __syncthreads();

  // ---- stage 6 (R33): conv3 32->8 3x3 as MFMA; 9 taps = 9 K=32 steps ----
  {
    const int lane = t & 63, wid = t >> 6;
    if (wid < 2) {
      const int c = lane & 15, kg = lane >> 4;
      int apx = wid * 16 + c; if (apx > 24) apx = 24;   // clamp garbage rows
      const int ay = apx / 5, ax = apx - ay * 5;
      const u16* C2u = (const u16*)&S[C2S];
      const u16* wb = wb3b + c * 32 + kg * 8;           // [tap][16 n][32 k]
      f32x4 acc = {0.f, 0.f, 0.f, 0.f};
#pragma unroll
      for (int ky = 0; ky < 3; ky++)
#pragma unroll
        for (int kx = 0; kx < 3; kx++) {
          const bf16x8 av = *(const bf16x8*)&C2u[((ay + ky) * 8 + (ax + kx)) * 40 + kg * 8];
          const bf16x8 bv = *(const bf16x8*)&wb[(ky * 3 + kx) * 512];
          acc = __builtin_amdgcn_mfma_f32_16x16x32_bf16(av, bv, acc, 0, 0, 0);
        }
      if (c < 8) {      // cols 8-15 are zero-weight garbage
        const float b3c = b3[c];
#pragma unroll
        for (int r = 0; r < 4; r++) {
          const int px = wid * 16 + kg * 4 + r;         // C row = kg*4+r
          if (px < 25) S[C3S + c * 25 + px] = lrelu(acc[r] + b3c);
        }
      }
    }
  }
  __syncthreads();

  // ---- stage 7: dense 200->64 partials, 4 chunks (56/56/56/32), float4 ----
  {
    const int o = t & 63, chunk = t >> 6;
    const int start = chunk * 56;
    const int cnt = (chunk == 3) ? 8 : 14;
    const float4* wr4 = (const float4*)&dw1[o * 200 + start];
    const float4* cr4 = (const float4*)&S[C3S + start];
    float acc = 0.f;
    for (int i = 0; i < cnt; i++) {   // runtime bound OK: memory only
      const float4 wv = wr4[i], cv = cr4[i];
      acc += wv.x * cv.x + wv.y * cv.y + wv.z * cv.z + wv.w * cv.w;
    }
    S[D1P + chunk * 64 + o] = acc;
  }
  __syncthreads();

  // ---- dense head: wave 0 only (R9); unroll 4 caps live float4s (R22) ----
  if (t < 64) {
    S[D1 + t] = lrelu(S[D1P + t] + S[D1P + 64 + t] + S[D1P + 128 + t] +
                      S[D1P + 192 + t] + db1[t]);
    __builtin_amdgcn_s_waitcnt(0); __builtin_amdgcn_wave_barrier();
    if (t < 32) {
      float acc = db2[t];
      const float4* wr = (const float4*)&dw2[t * 64];
      const float4* dr = (const float4*)&S[D1];
#pragma unroll 4
      for (int i = 0; i < 16; i++) acc = fma4(wr[i], dr[i], acc);
      S[D2 + t] = lrelu(acc);
    }
    __builtin_amdgcn_s_waitcnt(0); __builtin_amdgcn_wave_barrier();
    if (t < 16) {
      float acc = db3[t];
      const float4* wr = (const float4*)&dw3[t * 32];
      const float4* dr = (const float4*)&S[D2];
#pragma unroll 4
      for (int i = 0; i < 8; i++) acc = fma4(wr[i], dr[i], acc);
      S[D3 + t] = lrelu(acc);
    }
    __builtin_amdgcn_s_waitcnt(0); __builtin_amdgcn_wave_barrier();
    if (t < 8) {
      float acc = db4[t];
      const float4* wr = (const float4*)&dw4[t * 16];
      const float4* dr = (const float4*)&S[D3];
#pragma unroll
      for (int i = 0; i < 4; i++) acc = fma4(wr[i], dr[i], acc);
      S[D4 + t] = lrelu(acc);
    }
    __builtin_amdgcn_s_waitcnt(0); __builtin_amdgcn_wave_barrier();
    if (t < 2) {
      float acc = db5[t];
      const float4* wr = (const float4*)&dw5[t * 8];
      const float4* dr = (const float4*)&S[D4];
#pragma unroll
      for (int i = 0; i < 2; i++) acc = fma4(wr[i], dr[i], acc);
      out[(size_t)b * 2 + t] = acc;
    }
  }
}

extern "C" void kernel_launch(void* const* d_in, const int* in_sizes, int n_in,
                              void* d_out, int out_size, void* d_ws, size_t ws_size,
                              hipStream_t stream) {
  const float* x   = (const float*)d_in[0];
  const float* w1  = (const float*)d_in[1];
  const float* b1  = (const float*)d_in[2];
  const float* wt  = (const float*)d_in[3];
  const float* bt  = (const float*)d_in[4];
  const float* wp  = (const float*)d_in[5];
  const float* bp  = (const float*)d_in[6];
  const float* wg  = (const float*)d_in[7];
  const float* bg  = (const float*)d_in[8];
  const float* wo  = (const float*)d_in[9];
  const float* bo  = (const float*)d_in[10];
  const float* w2  = (const float*)d_in[11];
  const float* b2  = (const float*)d_in[12];
  const float* w3  = (const float*)d_in[13];
  const float* b3  = (const float*)d_in[14];
  const float* dw1 = (const float*)d_in[15];
  const float* db1 = (const float*)d_in[16];
  const float* dw2 = (const float*)d_in[17];
  const float* db2 = (const float*)d_in[18];
  const float* dw3 = (const float*)d_in[19];
  const float* db3 = (const float*)d_in[20];
  const float* dw4 = (const float*)d_in[21];
  const float* db4 = (const float*)d_in[22];
  const float* dw5 = (const float*)d_in[23];
  const float* db5 = (const float*)d_in[24];

  float* pw = (float*)d_ws;   // u16: wb2@0 wtpg@18432 wob@24576 wb3b@26624 wb1@31232
  repack_w23<<<32, 256, 0, stream>>>(w2, w3, wt, wp, wg, wo, w1, pw);
  const u16* wb2  = (const u16*)pw;
  const u16* wtpg = (const u16*)(pw + 9216);
  const u16* wob  = (const u16*)(pw + 12288);
  const u16* wb3b = (const u16*)(pw + 13312);
  const u16* wb1  = (const u16*)(pw + 15616);

  int B = in_sizes[0] / 121;
  braggnn_fused<<<B, 256, 0, stream>>>(
      x, wb1, b1, wtpg, bt, bp, bg, wob, bo, wb2, wb3b, b2, b3,
      dw1, db1, dw2, db2, dw3, db3, dw4, db4, dw5, db5,
      (float*)d_out);
}

// Round 18
// 610.772 us; speedup vs baseline: 1.0429x; 1.0429x over previous
//
#include <hip/hip_runtime.h>

#define NEG 0.01f
__device__ __forceinline__ float lrelu(float v){ return v >= 0.f ? v : NEG * v; }

typedef short bf16x8 __attribute__((ext_vector_type(8)));   // 8 bf16 = 4 VGPRs
typedef float f32x4 __attribute__((ext_vector_type(4)));
typedef unsigned short u16;

__device__ __forceinline__ u16 f2bf(float f) {   // RNE f32 -> bf16 (finite inputs)
  unsigned u = __float_as_uint(f);
  return (u16)((u + 0x7FFFu + ((u >> 16) & 1u)) >> 16);
}
__device__ __forceinline__ float bflo(unsigned u){ return __uint_as_float(u << 16); }
__device__ __forceinline__ float bfhi(unsigned u){ return __uint_as_float(u & 0xffff0000u); }
__device__ __forceinline__ float bfu(u16 v){ return __uint_as_float((unsigned)v << 16); }

__device__ __forceinline__ float fma4(float4 wv, float4 hv, float acc) {
  return fmaf(wv.x, hv.x, fmaf(wv.y, hv.y, fmaf(wv.z, hv.z, fmaf(wv.w, hv.w, acc))));
}

// ============================ RULES (final ledger) ============================
// (R2)  no runtime-bound loop may index a register array — full unroll only.
// (R9)  dense head in wave 0 only (s_waitcnt+wave_barrier ordering).
// (R14) MFMA 16x16x32 bf16 map (verified): A row m=l&15, k=8*(l>>4)+i; B col
//       n=l&15; C/D row=(l>>4)*4+reg, col=l&15. Garbage rows safe (discard).
// (R15) H2 bf16 from birth; residual rounds ONCE.
// (R16) VGPR cliff at 64. Nothing live across barriers + hard cap -> 40 VGPR.
// (R20/R31) serial p-loops & paired-patch 512-thr blocks: dead ends (r4/r13).
// (R22) unroll-1 on hot weight loops serializes latency; dense head unroll 4.
// (R24) stage-2a = MFMA GEMM [81x64]x[64x96] (T|P|G); G -> LDS bf16 stash.
// (R25) H2B row stride 36 u32 (144B): MFMA A-reads ~2-way.
// (R26) split retired (r7). (R27) stash regions FULL size (r8 bug).
// (R28) stage-4 = MFMA [81x32]x[32x64]; A = bf16(attn*G) built in-reg.
// (R29) stage-4 BARRIER-FREE: in-place H2B RMW on wave-own rows.
// (R30) SBH/G bf16 [81][40]: arena 6156 dw -> 6 blocks/CU.
// (R32) LIMITER = per-CU issue/latency floor. Deletion lever outcomes:
//       stage-6 MFMA (r14) -118us; stage-1 MFMA (r15) +4us noise;
//       operand-swap LDS-op deletion (r17) +14us, occ 64->42 (VGPR 52).
//       CONVERGED at r14 config: all pipes <=24%, occ 64%, 555us rocprof.
//       Do NOT retry: r15 stage-1 MFMA, r17 swap, r13 pairing, r5 diets.
// (R33) stage-6 = MFMA conv3, C2S bf16 [56][40]. (+18%, absmax unchanged.)

// -------- LDS arena: S[6156] dw = 24624 B -> 6 blocks/CU --------
// Phase A (0-4): H2B@0 u32[81][36] (2916) | SBH@2916 u16[81][40] (1620) |
//   XS@4536(121, dies st-1) | G@4536 u16[81][40] (1620, born 2a after XS dead).
// Stage 4: in-place H2B->H4 u16[81][72] @0 (R29, no barrier).
// Stage 5: A-reads H4@0 stride 144B (garbage rows in-arena, discarded),
//   writes C2S@2916 u16[56][40] (1120 dw, over dead SBH+G head).
// Stage 6 (R33): reads C2S@2916, writes C3S@1600 (over dead H4).
// Phase C: C3S@1600(200) D1P@1800(256) D1@2056 D2@2120 D3@2152 D4@2168.
#define H2B  0
#define SBH  2916
#define XS   4536
#define G0   4536
#define H4   0
#define C2S  2916
#define C3S  1600
#define D1P  1800
#define D1   2056
#define D2   2120
#define D3   2152
#define D4   2168

// repack (all bf16 u16): wb2 [tap9][oc32][ic64] @0 (18432)
//   wtpg [96 n][64 k] @18432 (6144) | wob [64 n][32 k] @24576 (2048)
//   wb3b [tap9][16 n][32 k] @26624 (4608; n>=8 zero)   total 31232 u16
__global__ void repack_w23(const float* __restrict__ w2, const float* __restrict__ w3,
                           const float* __restrict__ wt, const float* __restrict__ wp,
                           const float* __restrict__ wg, const float* __restrict__ wo,
                           float* __restrict__ pw) {
  int idx = blockIdx.x * 256 + threadIdx.x;
  u16* u = (u16*)pw;
  for (int i = idx; i < 31232; i += gridDim.x * 256) {
    if (i < 18432) {
      int ic = i & 63, oc = (i >> 6) & 31, tap = i >> 11;
      u[i] = f2bf(w2[(oc * 64 + ic) * 9 + tap]);
    } else if (i < 24576) {
      int j = i - 18432;                 // wtpg
      int k = j & 63, n = j >> 6;
      float v = (n < 32) ? wt[n * 64 + k]
              : (n < 64) ? wp[(n - 32) * 64 + k]
                         : wg[(n - 64) * 64 + k];
      u[i] = f2bf(v);
    } else if (i < 26624) {
      int j = i - 24576;                 // wob: [oc][ic]
      u[i] = f2bf(wo[j]);
    } else {
      int j = i - 26624;                 // wb3b: [tap][16 n][32 ic]
      int ic = j & 31, n = (j >> 5) & 15, tap = j >> 9;
      u[i] = (n < 8) ? f2bf(w3[(n * 32 + ic) * 9 + tap]) : (u16)0;
    }
  }
}

// stage-4 A-fragment: bf16(attn*G), both operands bf16 in LDS (R28/R30)
__device__ __forceinline__ bf16x8 st4_afrag(const float* S, int ar, int kg) {
  const uint4 sv = *(const uint4*)((const u16*)&S[SBH] + ar * 40 + kg * 8);
  const uint4 gv = *(const uint4*)((const u16*)&S[G0] + ar * 40 + kg * 8);
  unsigned q0 = (unsigned)f2bf(bflo(sv.x) * bflo(gv.x)) |
                ((unsigned)f2bf(bfhi(sv.x) * bfhi(gv.x)) << 16);
  unsigned q1 = (unsigned)f2bf(bflo(sv.y) * bflo(gv.y)) |
                ((unsigned)f2bf(bfhi(sv.y) * bfhi(gv.y)) << 16);
  unsigned q2 = (unsigned)f2bf(bflo(sv.z) * bflo(gv.z)) |
                ((unsigned)f2bf(bfhi(sv.z) * bfhi(gv.z)) << 16);
  unsigned q3 = (unsigned)f2bf(bflo(sv.w) * bflo(gv.w)) |
                ((unsigned)f2bf(bfhi(sv.w) * bfhi(gv.w)) << 16);
  union { uint4 u; bf16x8 b; } v; v.u = (uint4){q0, q1, q2, q3}; return v.b;
}

__global__ __launch_bounds__(256, 8) __attribute__((amdgpu_num_vgpr(64)))
void braggnn_fused(
    const float* __restrict__ x,
    const float* __restrict__ w1, const float* __restrict__ b1,
    const u16* __restrict__ wtpg,
    const float* __restrict__ bt, const float* __restrict__ bp,
    const float* __restrict__ bg,
    const u16* __restrict__ wob, const float* __restrict__ bo,
    const u16* __restrict__ wb2, const u16* __restrict__ wb3b,
    const float* __restrict__ b2, const float* __restrict__ b3,
    const float* __restrict__ dw1, const float* __restrict__ db1,
    const float* __restrict__ dw2, const float* __restrict__ db2,
    const float* __restrict__ dw3, const float* __restrict__ db3,
    const float* __restrict__ dw4, const float* __restrict__ db4,
    const float* __restrict__ dw5, const float* __restrict__ db5,
    float* __restrict__ out)
{
  const int b = blockIdx.x;
  const int t = threadIdx.x;

  __shared__ __align__(16) float S[6156];   // 24624 B

  // ---- stage 0: load 11x11 patch ----
  if (t < 121) S[XS + t] = x[(size_t)b * 121 + t];
  __syncthreads();

  // ---- stage 1: conv1 1->64 3x3, oc-PAIRED -> H2B bf16 [81][72s36] (R15/R25) ----
  {
    const int ocp = t & 31, pg = t >> 5;       // oc = 2*ocp, 2*ocp+1; pg 0..7
    float wreg[18];
#pragma unroll
    for (int i = 0; i < 18; i++) wreg[i] = w1[ocp * 18 + i];
    const float bv0 = b1[2 * ocp], bv1 = b1[2 * ocp + 1];
    for (int px = pg; px < 81; px += 8) {
      const int y = px / 9, xx = px - y * 9;
      const float* xr = &S[XS + y * 11 + xx];
      float a0 = bv0, a1 = bv1;
#pragma unroll
      for (int ky = 0; ky < 3; ky++)
#pragma unroll
        for (int kx = 0; kx < 3; kx++) {
          const float v = xr[ky * 11 + kx];
          a0 = fmaf(v, wreg[ky * 3 + kx], a0);
          a1 = fmaf(v, wreg[9 + ky * 3 + kx], a1);
        }
      ((unsigned*)S)[H2B + px * 36 + ocp] =
          (unsigned)f2bf(a0) | ((unsigned)f2bf(a1) << 16);
    }
  }
  __syncthreads();

  // ---- stage 2a (R24): theta/phi/g via MFMA; logits -> SBH bf16, g -> G ----
  {
    const int lane = t & 63, wid = t >> 6;
    const int c = lane & 15, kg = lane >> 4;
    const char* Sb = (const char*)S;          // H2B at byte 0, 144 B/row
    u16* SBu = (u16*)&S[SBH];
    u16* Gp  = (u16*)&S[G0];
#pragma unroll 1
    for (int r2 = 0; r2 < 2; r2++) {
      const int mt = wid + 4 * r2;
      if (mt >= 6) break;                     // wave-uniform
      const int arow = mt * 16 + c;           // px (rows 81-95: garbage, discarded)
      const bf16x8 a0 = *(const bf16x8*)(Sb + arow * 144 + kg * 16);
      const bf16x8 a1 = *(const bf16x8*)(Sb + arow * 144 + 64 + kg * 16);
#pragma unroll
      for (int ng = 0; ng < 2; ng++) {
        const u16* bl = wtpg + (ng * 16 + c) * 64 + kg * 8;
        const bf16x8 t0 = *(const bf16x8*)(bl);
        const bf16x8 t1 = *(const bf16x8*)(bl + 32);
        const bf16x8 p0 = *(const bf16x8*)(bl + 2048);       // +32 n
        const bf16x8 p1 = *(const bf16x8*)(bl + 2048 + 32);
        const bf16x8 g0 = *(const bf16x8*)(bl + 4096);       // +64 n
        const bf16x8 g1 = *(const bf16x8*)(bl + 4096 + 32);
        f32x4 aT = {0.f,0.f,0.f,0.f}, aP = {0.f,0.f,0.f,0.f}, aG = {0.f,0.f,0.f,0.f};
        aT = __builtin_amdgcn_mfma_f32_16x16x32_bf16(a0, t0, aT, 0, 0, 0);
        aT = __builtin_amdgcn_mfma_f32_16x16x32_bf16(a1, t1, aT, 0, 0, 0);
        aP = __builtin_amdgcn_mfma_f32_16x16x32_bf16(a0, p0, aP, 0, 0, 0);
        aP = __builtin_amdgcn_mfma_f32_16x16x32_bf16(a1, p1, aP, 0, 0, 0);
        aG = __builtin_amdgcn_mfma_f32_16x16x32_bf16(a0, g0, aG, 0, 0, 0);
        aG = __builtin_amdgcn_mfma_f32_16x16x32_bf16(a1, g1, aG, 0, 0, 0);
        const int oc = ng * 16 + c;
        const float bT = bt[oc], bP = bp[oc], bG = bg[oc];
#pragma unroll
        for (int r = 0; r < 4; r++) {
          const int px = mt * 16 + kg * 4 + r;  // C row = (l>>4)*4 + reg (R14)
          if (px <= 80) {
            SBu[px * 40 + oc] = f2bf((aT[r] + bT) * (aP[r] + bP));   // R30
            Gp[px * 40 + oc]  = f2bf(aG[r] + bG);
          }
        }
      }
    }
  }
  __syncthreads();

  // ---- stage 2 pass B: softmax over W (9), bf16 in/out, f32 compute (R30) ----
  {
    u16* SBu = (u16*)&S[SBH];
    auto sm = [&](int r) {
      const int oc = r & 31, y = r >> 5;
      const int base = y * 9 * 40 + oc;       // u16 index; px = y*9+k
      float v[9]; float m = -1e30f;
#pragma unroll
      for (int k = 0; k < 9; k++) { v[k] = bfu(SBu[base + k * 40]); m = fmaxf(m, v[k]); }
      float s = 0.f;
#pragma unroll
      for (int k = 0; k < 9; k++) { v[k] = __expf(v[k] - m); s += v[k]; }
      const float inv = 1.f / s;
#pragma unroll
      for (int k = 0; k < 9; k++) SBu[base + k * 40] = f2bf(v[k] * inv);
    };
    sm(t);
    if (t < 32) sm(256 + t);
  }
  __syncthreads();

  // ---- stage 4 (R28/R29): wo 1x1 as MFMA, BARRIER-FREE, in-place H2B RMW ----
  {
    const int lane = t & 63, wid = t >> 6;
    const int c = lane & 15, kg = lane >> 4;
    const u16* wbp = wob + c * 32 + kg * 8;
    const bf16x8 b0 = *(const bf16x8*)(wbp);
    const bf16x8 b1v = *(const bf16x8*)(wbp + 512);   // +16 n
    const bf16x8 b2v = *(const bf16x8*)(wbp + 1024);  // +32 n
    const bf16x8 b3v = *(const bf16x8*)(wbp + 1536);  // +48 n
    const f32x4 z = {0.f, 0.f, 0.f, 0.f};
    u16* Hw = (u16*)S;      // H2B/H4 u16 view: idx = px*72 + oc (same address!)
#define ST4EPI(MT, ACC, NT) { \
      const int oc_ = (NT) * 16 + c; \
      const float bov_ = bo[oc_]; \
      _Pragma("unroll") \
      for (int r = 0; r < 4; r++) { \
        const int px_ = (MT) * 16 + kg * 4 + r; \
        if (px_ <= 80) { \
          const int idx_ = px_ * 72 + oc_; \
          Hw[idx_] = f2bf(lrelu((ACC[r] + bfu(Hw[idx_])) + bov_)); \
        } \
      } }
    {   // m-tile 0: rows [16*wid, 16*wid+16) — own rows only (R29)
      const bf16x8 a0 = st4_afrag(S, wid * 16 + c, kg);
      f32x4 A0 = __builtin_amdgcn_mfma_f32_16x16x32_bf16(a0, b0, z, 0, 0, 0);
      f32x4 A1 = __builtin_amdgcn_mfma_f32_16x16x32_bf16(a0, b1v, z, 0, 0, 0);
      f32x4 A2 = __builtin_amdgcn_mfma_f32_16x16x32_bf16(a0, b2v, z, 0, 0, 0);
      f32x4 A3 = __builtin_amdgcn_mfma_f32_16x16x32_bf16(a0, b3v, z, 0, 0, 0);
      ST4EPI(wid, A0, 0) ST4EPI(wid, A1, 1) ST4EPI(wid, A2, 2) ST4EPI(wid, A3, 3)
    }
    if (wid < 2) {   // m-tile 1: rows [16*(wid+4), ...) clamped to 80
      int ar1 = (wid + 4) * 16 + c; if (ar1 > 80) ar1 = 80;
      const bf16x8 a1 = st4_afrag(S, ar1, kg);
      f32x4 A0 = __builtin_amdgcn_mfma_f32_16x16x32_bf16(a1, b0, z, 0, 0, 0);
      f32x4 A1 = __builtin_amdgcn_mfma_f32_16x16x32_bf16(a1, b1v, z, 0, 0, 0);
      f32x4 A2 = __builtin_amdgcn_mfma_f32_16x16x32_bf16(a1, b2v, z, 0, 0, 0);
      f32x4 A3 = __builtin_amdgcn_mfma_f32_16x16x32_bf16(a1, b3v, z, 0, 0, 0);
      const int mtB = wid + 4;
      ST4EPI(mtB, A0, 0) ST4EPI(mtB, A1, 1) ST4EPI(mtB, A2, 2) ST4EPI(mtB, A3, 3)
    }
  }
  __syncthreads();

  // ---- stage 5 (R14): conv2 64->32 3x3 as bf16 MFMA 16x16x32 ----
  {
    const int lane = t & 63, wid = t >> 6;
    const int m = lane & 15, kg = lane >> 4;      // A row, k-group
    const int opx = wid * 16 + m;                 // output px this lane feeds
    const int oy = opx / 7, ox = opx - oy * 7;
    const char* Sb = (const char*)S;
    int aoff = (oy * 9 + ox) * 144 + kg * 16;     // bytes into H4@0 (144 B/row)
    const u16* wbl = wb2 + (lane & 15) * 64 + kg * 8;
    f32x4 acc0 = {0.f, 0.f, 0.f, 0.f}, acc1 = {0.f, 0.f, 0.f, 0.f};
#pragma unroll 1
    for (int ky = 0; ky < 3; ky++) {
#pragma unroll
      for (int kx = 0; kx < 3; kx++) {
#pragma unroll
        for (int ks = 0; ks < 2; ks++) {
          const bf16x8 av = *(const bf16x8*)(Sb + (aoff + kx * 144 + ks * 64));
          const bf16x8 b0v = *(const bf16x8*)(wbl + kx * 2048 + ks * 32);
          const bf16x8 b1v = *(const bf16x8*)(wbl + kx * 2048 + ks * 32 + 1024);
          acc0 = __builtin_amdgcn_mfma_f32_16x16x32_bf16(av, b0v, acc0, 0, 0, 0);
          acc1 = __builtin_amdgcn_mfma_f32_16x16x32_bf16(av, b1v, acc1, 0, 0, 0);
        }
      }
      aoff += 9 * 144;        // next ky input row
      wbl  += 3 * 2048;       // next ky tap group
    }
    // epilogue (R33): bias + lrelu -> C2S bf16 [56 rows][40 u16] @2916
    // (over dead SBH+G head; garbage A-reads into this region are discarded).
    u16* C2u = (u16*)&S[C2S];
#pragma unroll
    for (int nt = 0; nt < 2; nt++) {
      const f32x4 accv = nt ? acc1 : acc0;
      const int oc = nt * 16 + (lane & 15);
      const float bv = b2[oc];
#pragma unroll
      for (int r = 0; r < 4; r++) {
        const int px = wid * 16 + kg * 4 + r;     // C row = (lane>>4)*4 + reg
        if (px < 49) {
          const int y = px / 7, xx = px - y * 7;
          C2u[(y * 8 + xx) * 40 + oc] = f2bf(lrelu(accv[r] + bv));
        }
      }
    }
  }
  __syncthreads();

  // ---- stage 6 (R33): conv3 32->8 3x3 as MFMA; 9 taps = 9 K=32 steps ----
  {
    const int lane = t & 63, wid = t >> 6;
    if (wid < 2) {
      const int c = lane & 15, kg = lane >> 4;
      int apx = wid * 16 + c; if (apx > 24) apx = 24;   // clamp garbage rows
      const int ay = apx / 5, ax = apx - ay * 5;
      const u16* C2u = (const u16*)&S[C2S];
      const u16* wb = wb3b + c * 32 + kg * 8;           // [tap][16 n][32 k]
      f32x4 acc = {0.f, 0.f, 0.f, 0.f};
#pragma unroll
      for (int ky = 0; ky < 3; ky++)
#pragma unroll
        for (int kx = 0; kx < 3; kx++) {
          const bf16x8 av = *(const bf16x8*)&C2u[((ay + ky) * 8 + (ax + kx)) * 40 + kg * 8];
          const bf16x8 bv = *(const bf16x8*)&wb[(ky * 3 + kx) * 512];
          acc = __builtin_amdgcn_mfma_f32_16x16x32_bf16(av, bv, acc, 0, 0, 0);
        }
      if (c < 8) {      // cols 8-15 are zero-weight garbage
        const float b3c = b3[c];
#pragma unroll
        for (int r = 0; r < 4; r++) {
          const int px = wid * 16 + kg * 4 + r;         // C row = kg*4+r
          if (px < 25) S[C3S + c * 25 + px] = lrelu(acc[r] + b3c);
        }
      }
    }
  }
  __syncthreads();

  // ---- stage 7: dense 200->64 partials, 4 chunks (56/56/56/32), float4 ----
  {
    const int o = t & 63, chunk = t >> 6;
    const int start = chunk * 56;
    const int cnt = (chunk == 3) ? 8 : 14;
    const float4* wr4 = (const float4*)&dw1[o * 200 + start];
    const float4* cr4 = (const float4*)&S[C3S + start];
    float acc = 0.f;
    for (int i = 0; i < cnt; i++) {   // runtime bound OK: memory only
      const float4 wv = wr4[i], cv = cr4[i];
      acc += wv.x * cv.x + wv.y * cv.y + wv.z * cv.z + wv.w * cv.w;
    }
    S[D1P + chunk * 64 + o] = acc;
  }
  __syncthreads();

  // ---- dense head: wave 0 only (R9); unroll 4 caps live float4s (R22) ----
  if (t < 64) {
    S[D1 + t] = lrelu(S[D1P + t] + S[D1P + 64 + t] + S[D1P + 128 + t] +
                      S[D1P + 192 + t] + db1[t]);
    __builtin_amdgcn_s_waitcnt(0); __builtin_amdgcn_wave_barrier();
    if (t < 32) {
      float acc = db2[t];
      const float4* wr = (const float4*)&dw2[t * 64];
      const float4* dr = (const float4*)&S[D1];
#pragma unroll 4
      for (int i = 0; i < 16; i++) acc = fma4(wr[i], dr[i], acc);
      S[D2 + t] = lrelu(acc);
    }
    __builtin_amdgcn_s_waitcnt(0); __builtin_amdgcn_wave_barrier();
    if (t < 16) {
      float acc = db3[t];
      const float4* wr = (const float4*)&dw3[t * 32];
      const float4* dr = (const float4*)&S[D2];
#pragma unroll 4
      for (int i = 0; i < 8; i++) acc = fma4(wr[i], dr[i], acc);
      S[D3 + t] = lrelu(acc);
    }
    __builtin_amdgcn_s_waitcnt(0); __builtin_amdgcn_wave_barrier();
    if (t < 8) {
      float acc = db4[t];
      const float4* wr = (const float4*)&dw4[t * 16];
      const float4* dr = (const float4*)&S[D3];
#pragma unroll
      for (int i = 0; i < 4; i++) acc = fma4(wr[i], dr[i], acc);
      S[D4 + t] = lrelu(acc);
    }
    __builtin_amdgcn_s_waitcnt(0); __builtin_amdgcn_wave_barrier();
    if (t < 2) {
      float acc = db5[t];
      const float4* wr = (const float4*)&dw5[t * 8];
      const float4* dr = (const float4*)&S[D4];
#pragma unroll
      for (int i = 0; i < 2; i++) acc = fma4(wr[i], dr[i], acc);
      out[(size_t)b * 2 + t] = acc;
    }
  }
}

extern "C" void kernel_launch(void* const* d_in, const int* in_sizes, int n_in,
                              void* d_out, int out_size, void* d_ws, size_t ws_size,
                              hipStream_t stream) {
  const float* x   = (const float*)d_in[0];
  const float* w1  = (const float*)d_in[1];
  const float* b1  = (const float*)d_in[2];
  const float* wt  = (const float*)d_in[3];
  const float* bt  = (const float*)d_in[4];
  const float* wp  = (const float*)d_in[5];
  const float* bp  = (const float*)d_in[6];
  const float* wg  = (const float*)d_in[7];
  const float* bg  = (const float*)d_in[8];
  const float* wo  = (const float*)d_in[9];
  const float* bo  = (const float*)d_in[10];
  const float* w2  = (const float*)d_in[11];
  const float* b2  = (const float*)d_in[12];
  const float* w3  = (const float*)d_in[13];
  const float* b3  = (const float*)d_in[14];
  const float* dw1 = (const float*)d_in[15];
  const float* db1 = (const float*)d_in[16];
  const float* dw2 = (const float*)d_in[17];
  const float* db2 = (const float*)d_in[18];
  const float* dw3 = (const float*)d_in[19];
  const float* db3 = (const float*)d_in[20];
  const float* dw4 = (const float*)d_in[21];
  const float* db4 = (const float*)d_in[22];
  const float* dw5 = (const float*)d_in[23];
  const float* db5 = (const float*)d_in[24];

  float* pw = (float*)d_ws;   // u16 layout: wb2@0 wtpg@18432 wob@24576 wb3b@26624
  repack_w23<<<32, 256, 0, stream>>>(w2, w3, wt, wp, wg, wo, pw);
  const u16* wb2  = (const u16*)pw;
  const u16* wtpg = (const u16*)(pw + 9216);
  const u16* wob  = (const u16*)(pw + 12288);
  const u16* wb3b = (const u16*)(pw + 13312);

  int B = in_sizes[0] / 121;
  braggnn_fused<<<B, 256, 0, stream>>>(
      x, w1, b1, wtpg, bt, bp, bg, wob, bo, wb2, wb3b, b2, b3,
      dw1, db1, dw2, db2, dw3, db3, dw4, db4, dw5, db5,
      (float*)d_out);
}